// Round 4
// baseline (775.277 us; speedup 1.0000x reference)
//
#include <hip/hip_runtime.h>
#include <hip/hip_bf16.h>
#include <stdint.h>

#define S_ 2048
#define D_ 1024
#define B_ 8
#define KEXP 3072            // 3 * D : [h,l,h] x [h,h,l] fp16 expansion
#define NEGC 1e9f

typedef _Float16 f16;
typedef _Float16 f16x8 __attribute__((ext_vector_type(8)));
typedef float f32x4 __attribute__((ext_vector_type(4)));

// LDS swizzle: involution on byte offsets within a [row][64B] slot.
// Flips byte bits 4-5 by row bits 1-2: 16-lane same-col fragment reads land
// 2-way per bank = free (m136). Verified 0 SQ_LDS_BANK_CONFLICT in R3.
__device__ __forceinline__ int swz(int x) { return x ^ (((x >> 7) & 3) << 4); }

// ---------------------------------------------------------------------------
// K0: split fp32 -> fp16 hi/lo 3-term expansion, input pre-scaled by 64.
// pattern A (q): [h,l,h]   pattern B (k): [h,h,l]
// blockIdx.y selects q (0) or k (1) — one launch for both.
// ---------------------------------------------------------------------------
__global__ __launch_bounds__(256) void split_expand2(const float* __restrict__ qin,
                                                     const float* __restrict__ kin,
                                                     f16* __restrict__ qx,
                                                     f16* __restrict__ kx) {
  const int isB = blockIdx.y;
  const float* in = isB ? kin : qin;
  f16* out = isB ? kx : qx;
  size_t idx = (size_t)blockIdx.x * 256 + threadIdx.x;   // one thread per 8 floats
  const float4* ip = (const float4*)(in + idx * 8);
  float4 a = ip[0], b = ip[1];
  float vv[8] = {a.x, a.y, a.z, a.w, b.x, b.y, b.z, b.w};
  union { f16 h[24]; uint4 u[3]; } o;
#pragma unroll
  for (int t = 0; t < 8; ++t) {
    float v = vv[t] * 64.0f;
    f16 h = (f16)v;
    float r = v - (float)h;      // exact (Sterbenz)
    f16 l = (f16)r;
    o.h[3 * t + 0] = h;
    o.h[3 * t + 1] = isB ? h : l;
    o.h[3 * t + 2] = isB ? l : h;
  }
  uint4* op = (uint4*)(out + idx * 24);
  op[0] = o.u[0]; op[1] = o.u[1]; op[2] = o.u[2];
}

// ---------------------------------------------------------------------------
// K0c: khT[b][d][j] = fp16(k[b][j][d])  (plain cast, no prescale) for PV GEMM
// ---------------------------------------------------------------------------
__global__ __launch_bounds__(256) void transpose_cast(const float* __restrict__ k,
                                                      f16* __restrict__ khT) {
  __shared__ f16 tile[64][65];
  int j0 = blockIdx.x * 64, d0 = blockIdx.y * 64;
  size_t bz = blockIdx.z;
  const float* kb = k + bz * (size_t)S_ * D_;
  f16* ob = khT + bz * (size_t)D_ * S_;
#pragma unroll
  for (int i = 0; i < 16; ++i) {
    int e = threadIdx.x + i * 256;
    int r = e >> 6, c = e & 63;              // r: j-local, c: d-local
    tile[c][r] = (f16)kb[(size_t)(j0 + r) * D_ + d0 + c];
  }
  __syncthreads();
#pragma unroll
  for (int i = 0; i < 16; ++i) {
    int e = threadIdx.x + i * 256;
    int r = e >> 6, c = e & 63;              // r: d-local, c: j-local
    ob[(size_t)(d0 + r) * S_ + j0 + c] = tile[r][c];
  }
}

// ---------------------------------------------------------------------------
// GEMM (B-transposed): C[m,n] = (sum_k A[m,k]*B[n,k]) * mult
// 256xBN tile, BK=32, 8 waves (2M x 4N), ring-3 LDS, prefetch depth 2,
// ONE barrier per K-tile + counted vmcnt (never drains in main loop).
// Safety: reads of slot s complete (lgkmcnt before MFMA issue) before the
// tile-end barrier; the overwrite of s is issued one tile later; staged data
// for tile t+1 is published by vmcnt(LPT)+barrier at end of tile t.
// K-accumulation order identical across variants -> bit-identical results.
// ---------------------------------------------------------------------------
template <int KA, int NN, int BN>
__global__ __launch_bounds__(512, 2) void gemm256(const f16* __restrict__ A,
                                                  const f16* __restrict__ Bm,
                                                  float* __restrict__ C,
                                                  const float* scale_ptr, float factor) {
  constexpr int NF = BN / 64;          // B fragments per wave (4 or 2)
  constexpr int BR = BN / 128;         // stageB rounds (2 or 1)
  __shared__ f16 As[3][256 * 32];      // 3 x 16 KB
  __shared__ f16 Bs[3][BN * 32];       // 3 x (16 or 8) KB
  const int tid = threadIdx.x;
  const int lane = tid & 63, wave = tid >> 6;
  const int wm = wave >> 2, wn = wave & 3;          // 2 x 4 wave grid
  const size_t bz = blockIdx.z;
  const f16* Ab = A + bz * (size_t)S_ * KA + (size_t)blockIdx.x * 256 * KA;
  const f16* Bb = Bm + bz * (size_t)NN * KA + (size_t)blockIdx.y * BN * KA;

  // staging: linear LDS dest (global_load_lds), inverse-swizzled global source
  int prow[2], pcol[2];
#pragma unroll
  for (int i = 0; i < 2; ++i) {
    int p = i * 8192 + wave * 1024 + lane * 16;   // physical byte in slot
    int l = swz(p);                               // logical byte (involution)
    prow[i] = l >> 6;
    pcol[i] = (l & 63) >> 1;
  }

  f32x4 acc[8][NF];
#pragma unroll
  for (int i = 0; i < 8; ++i)
#pragma unroll
    for (int j = 0; j < NF; ++j)
#pragma unroll
      for (int r = 0; r < 4; ++r) acc[i][j][r] = 0.0f;

  auto stageA = [&](int slot, int kt) {
#pragma unroll
    for (int i = 0; i < 2; ++i) {
      const f16* src = Ab + (size_t)prow[i] * KA + kt * 32 + pcol[i];
      f16* dst = &As[slot][i * 4096 + wave * 512];   // wave-uniform base
      __builtin_amdgcn_global_load_lds((const __attribute__((address_space(1))) void*)src,
                                       (__attribute__((address_space(3))) void*)dst, 16, 0, 0);
    }
  };
  auto stageB = [&](int slot, int kt) {
#pragma unroll
    for (int i = 0; i < BR; ++i) {
      const f16* src = Bb + (size_t)prow[i] * KA + kt * 32 + pcol[i];
      f16* dst = &Bs[slot][i * 4096 + wave * 512];
      __builtin_amdgcn_global_load_lds((const __attribute__((address_space(1))) void*)src,
                                       (__attribute__((address_space(3))) void*)dst, 16, 0, 0);
    }
  };

  const int cb = (lane >> 4) * 16;    // fragment k-chunk byte offset
  const int fr = lane & 15;           // fragment row within 16

  // one K-tile: stage(t+2) || 12 ds_read || 32 MFMA ; vmcnt ; barrier
  auto do_tile = [&](int t, int sk, int vm) {
    const int slot = t % 3;
    if (sk >= 0) { stageA((t + 2) % 3, sk); stageB((t + 2) % 3, sk); }
    const char* as = (const char*)&As[slot][0];
    const char* bs = (const char*)&Bs[slot][0];
    f16x8 af[4], bf[NF];
#pragma unroll
    for (int n = 0; n < NF; ++n) {
      int L = (wn * (BN / 4) + n * 16 + fr) * 64 + cb;
      bf[n] = *(const f16x8*)(bs + swz(L));
    }
#pragma unroll
    for (int m = 0; m < 4; ++m) {
      int L = (wm * 128 + m * 16 + fr) * 64 + cb;
      af[m] = *(const f16x8*)(as + swz(L));
    }
    __builtin_amdgcn_s_setprio(1);
#pragma unroll
    for (int m = 0; m < 4; ++m)
#pragma unroll
      for (int n = 0; n < NF; ++n)
        acc[m][n] = __builtin_amdgcn_mfma_f32_16x16x32_f16(af[m], bf[n], acc[m][n], 0, 0, 0);
    __builtin_amdgcn_s_setprio(0);
#pragma unroll
    for (int m = 0; m < 4; ++m) {
      int L = (wm * 128 + (m + 4) * 16 + fr) * 64 + cb;
      af[m] = *(const f16x8*)(as + swz(L));
    }
    __builtin_amdgcn_s_setprio(1);
#pragma unroll
    for (int m = 0; m < 4; ++m)
#pragma unroll
      for (int n = 0; n < NF; ++n)
        acc[m + 4][n] = __builtin_amdgcn_mfma_f32_16x16x32_f16(af[m], bf[n], acc[m + 4][n], 0, 0, 0);
    __builtin_amdgcn_s_setprio(0);
    if (vm > 0) {          // steady state: keep LPT loads (next tile's) in flight
      if constexpr (BN == 256) asm volatile("s_waitcnt vmcnt(4)" ::: "memory");
      else                     asm volatile("s_waitcnt vmcnt(3)" ::: "memory");
    } else if (vm == 0) {
      asm volatile("s_waitcnt vmcnt(0)" ::: "memory");
    }
    __builtin_amdgcn_s_barrier();
  };

  constexpr int NT = KA / 32;
  // prologue: tiles 0 and 1 in flight; wait for tile 0 only
  stageA(0, 0); stageB(0, 0);
  stageA(1, 1); stageB(1, 1);
  if constexpr (BN == 256) asm volatile("s_waitcnt vmcnt(4)" ::: "memory");
  else                     asm volatile("s_waitcnt vmcnt(3)" ::: "memory");
  __builtin_amdgcn_s_barrier();

#pragma unroll 1
  for (int t = 0; t <= NT - 3; ++t) do_tile(t, t + 2, 1);
  do_tile(NT - 2, -1, 0);
  do_tile(NT - 1, -1, -1);

  float scl = factor;
  if (scale_ptr != nullptr) scl = factor * scale_ptr[0];
  float* Cb = C + bz * (size_t)S_ * NN;
  const int rowb = blockIdx.x * 256 + wm * 128 + ((lane >> 4) << 2);
  const int colb = blockIdx.y * BN + wn * (BN / 4) + fr;
#pragma unroll
  for (int i = 0; i < 8; ++i)
#pragma unroll
    for (int j = 0; j < NF; ++j)
#pragma unroll
      for (int r = 0; r < 4; ++r)
        Cb[(size_t)(rowb + i * 16 + r) * NN + colb + j * 16] = acc[i][j][r] * scl;
}

// ---------------------------------------------------------------------------
// reductions
// ---------------------------------------------------------------------------
__device__ __forceinline__ float block_reduce_max(float v, float* red, int tid) {
#pragma unroll
  for (int o = 32; o > 0; o >>= 1) v = fmaxf(v, __shfl_xor(v, o, 64));
  __syncthreads();
  if ((tid & 63) == 0) red[tid >> 6] = v;
  __syncthreads();
  return fmaxf(fmaxf(red[0], red[1]), fmaxf(red[2], red[3]));
}
__device__ __forceinline__ float block_reduce_sum(float v, float* red, int tid) {
#pragma unroll
  for (int o = 32; o > 0; o >>= 1) v += __shfl_xor(v, o, 64);
  __syncthreads();
  if ((tid & 63) == 0) red[4 + (tid >> 6)] = v;
  __syncthreads();
  return (red[4] + red[5]) + (red[6] + red[7]);
}

// ---------------------------------------------------------------------------
// K2: row softmax for VALID query rows; padding rows -> P row = 0.
// ---------------------------------------------------------------------------
__global__ __launch_bounds__(256) void softmax_rows(const float* __restrict__ scores,
                                                    const int* __restrict__ mask,
                                                    f16* __restrict__ P, int b0) {
  __shared__ float red[8];
  const int q = blockIdx.x, bl = blockIdx.y, bg = b0 + bl;
  const int tid = threadIdx.x;
  const float* srow = scores + ((size_t)bl * S_ + q) * S_;
  f16* prow = P + ((size_t)bl * S_ + q) * S_;
  if (mask[bg * S_ + q] == 0) {
    uint4 z = {0, 0, 0, 0};
    ((uint4*)prow)[tid] = z;   // 256 threads x 16B = 4096B row
    return;
  }
  const int j0 = tid * 8;
  float4 s0v = *(const float4*)(srow + j0);
  float4 s1v = *(const float4*)(srow + j0 + 4);
  int4 m0 = *(const int4*)(mask + (size_t)bg * S_ + j0);
  int4 m1 = *(const int4*)(mask + (size_t)bg * S_ + j0 + 4);
  float sv[8] = {s0v.x, s0v.y, s0v.z, s0v.w, s1v.x, s1v.y, s1v.z, s1v.w};
  int mk[8] = {m0.x, m0.y, m0.z, m0.w, m1.x, m1.y, m1.z, m1.w};
  int fl[8];
  float lm = -3.4e38f;
#pragma unroll
  for (int i = 0; i < 8; ++i) {
    fl[i] = (j0 + i <= q) && (mk[i] != 0);
    if (fl[i]) lm = fmaxf(lm, sv[i]);
  }
  float m = block_reduce_max(lm, red, tid);
  float ls = 0.0f;
#pragma unroll
  for (int i = 0; i < 8; ++i) {
    float e = fl[i] ? expf(sv[i] - m) : 0.0f;
    sv[i] = e; ls += e;
  }
  float sum = block_reduce_sum(ls, red, tid);
  float inv = 1.0f / sum;
  union { f16 h[8]; uint4 u; } ow;
#pragma unroll
  for (int i = 0; i < 8; ++i) ow.h[i] = (f16)(sv[i] * inv);
  *(uint4*)(prow + j0) = ow.u;
}

// ---------------------------------------------------------------------------
// K4: padding query rows — replicate fp32 quantization of fl(s-1e9):
// softmax = uniform mean over the top 64-wide bucket; boundary entries get
// an exact (double) recompute. Ordered match list via block prefix scan.
// ---------------------------------------------------------------------------
__global__ __launch_bounds__(256) void padrows(const float* __restrict__ scores,
                                               const int* __restrict__ mask,
                                               const float* __restrict__ qg,
                                               const float* __restrict__ kg,
                                               const float* __restrict__ scale_ptr,
                                               float* __restrict__ out, int b0) {
  const int q = blockIdx.x, bl = blockIdx.y, bg = b0 + bl;
  if (mask[bg * S_ + q] != 0) return;
  const int tid = threadIdx.x;
  __shared__ int idxs[S_];
  __shared__ int scn[256];
  __shared__ float red[8];
  const float* srow = scores + ((size_t)bl * S_ + q) * S_;
  const float scl = scale_ptr[0];
  const int j0 = tid * 8;

  float4 s0v = *(const float4*)(srow + j0);
  float4 s1v = *(const float4*)(srow + j0 + 4);
  float sv[8] = {s0v.x, s0v.y, s0v.z, s0v.w, s1v.x, s1v.y, s1v.z, s1v.w};
  float vv[8];
  float lm = -3.4e38f;
#pragma unroll
  for (int i = 0; i < 8; ++i) {
    vv[i] = sv[i] - NEGC;             // fl(s - 1e9): quantized to 64-grid
    lm = fmaxf(lm, vv[i]);
  }
  float g0 = block_reduce_max(lm, red, tid);

  float lm2 = -3.4e38f;
#pragma unroll 1
  for (int i = 0; i < 8; ++i) {
    float s = sv[i];
    float t = s * (1.0f / 64.0f);     // exact scaling by power of 2
    float rn = rintf(t);
    float dist = (0.5f - fabsf(t - rn)) * 64.0f;   // distance to rounding boundary
    float v = vv[i];
    if (dist < 1e-3f && v >= g0 - 64.5f) {
      const float* qr = qg + ((size_t)bg * S_ + q) * D_;
      const float* kr = kg + ((size_t)bg * S_ + j0 + i) * D_;
      double acc = 0.0;
      for (int t2 = 0; t2 < D_; ++t2) acc += (double)qr[t2] * (double)kr[t2];
      float sx = (float)acc * scl;
      v = sx - NEGC;
    }
    vv[i] = v;
    lm2 = fmaxf(lm2, v);
  }
  float gf = block_reduce_max(lm2, red, tid);

  // ordered (j-sorted) match collection via block prefix scan
  int local = 0, flags = 0;
#pragma unroll
  for (int i = 0; i < 8; ++i) {
    int mt = (vv[i] == gf) ? 1 : 0;
    flags |= mt << i;
    local += mt;
  }
  scn[tid] = local;
  __syncthreads();
#pragma unroll
  for (int o = 1; o < 256; o <<= 1) {
    int v2 = (tid >= o) ? scn[tid - o] : 0;
    __syncthreads();
    scn[tid] += v2;
    __syncthreads();
  }
  int total = scn[255];
  int base = scn[tid] - local;
  int w = 0;
#pragma unroll
  for (int i = 0; i < 8; ++i)
    if ((flags >> i) & 1) idxs[base + (w++)] = j0 + i;
  __syncthreads();

  // cooperative mean over matched k rows (thread owns 4 d-columns)
  const float* kb = kg + (size_t)bg * S_ * D_;
  float a0 = 0, a1 = 0, a2 = 0, a3 = 0;
#pragma unroll 4
  for (int m2 = 0; m2 < total; ++m2) {
    const float4 kv = *(const float4*)(kb + (size_t)idxs[m2] * D_ + tid * 4);
    a0 += kv.x; a1 += kv.y; a2 += kv.z; a3 += kv.w;
  }
  float invc = 1.0f / (float)total;
  float4 o = {a0 * invc, a1 * invc, a2 * invc, a3 * invc};
  *(float4*)(out + ((size_t)bg * S_ + q) * D_ + tid * 4) = o;
}

// ---------------------------------------------------------------------------
extern "C" void kernel_launch(void* const* d_in, const int* in_sizes, int n_in,
                              void* d_out, int out_size, void* d_ws, size_t ws_size,
                              hipStream_t stream) {
  (void)in_sizes; (void)n_in; (void)out_size;
  const float* q = (const float*)d_in[0];
  const float* k = (const float*)d_in[1];
  const int* mask = (const int*)d_in[2];
  const float* scale = (const float*)d_in[3];
  float* out = (float*)d_out;

  const size_t per_qx = (size_t)S_ * KEXP * 2;     // 12.58 MB
  const size_t per_khT = (size_t)D_ * S_ * 2;      //  4.19 MB
  const size_t per_sc = (size_t)S_ * S_ * 4;       // 16.78 MB
  // P (8.39 MB) overlays qx (dead after the QK^T GEMM)
  const size_t per_batch = 2 * per_qx + per_khT + per_sc;

  int nb = (int)(ws_size / per_batch);
  if (nb > B_) nb = B_;
  if (nb < 1) nb = 1;

  char* w = (char*)d_ws;
  f16* qx = (f16*)w;
  f16* kx = (f16*)(w + (size_t)nb * per_qx);
  f16* khT = (f16*)(w + (size_t)nb * per_qx * 2);
  float* sc = (float*)(w + (size_t)nb * (per_qx * 2 + per_khT));
  f16* P = qx;                                     // overlay

  for (int b0 = 0; b0 < B_; b0 += nb) {
    int cb = (B_ - b0 < nb) ? (B_ - b0) : nb;
    const float* qb = q + (size_t)b0 * S_ * D_;
    const float* kb = k + (size_t)b0 * S_ * D_;

    int blocks0 = cb * ((S_ * D_ / 8) / 256);  // cb * 1024
    split_expand2<<<dim3(blocks0, 2), dim3(256), 0, stream>>>(qb, kb, qx, kx);
    transpose_cast<<<dim3(S_ / 64, D_ / 64, cb), dim3(256), 0, stream>>>(kb, khT);

    // scores = (q.k) * scale : factor 2^-12 undoes the 64x prescale on q,k
    gemm256<KEXP, S_, 256><<<dim3(8, 8, cb), dim3(512), 0, stream>>>(
        qx, kx, sc, scale, 0.000244140625f);

    softmax_rows<<<dim3(S_, cb), dim3(256), 0, stream>>>(sc, mask, P, b0);

    gemm256<S_, D_, 128><<<dim3(8, 8, cb), dim3(512), 0, stream>>>(
        P, khT, out + (size_t)b0 * S_ * D_, nullptr, 1.0f);

    padrows<<<dim3(S_, cb), dim3(256), 0, stream>>>(sc, mask, q, k, scale, out, b0);
  }
}

// Round 5
// 578.922 us; speedup vs baseline: 1.3392x; 1.3392x over previous
//
#include <hip/hip_runtime.h>
#include <hip/hip_bf16.h>
#include <stdint.h>

#define S_ 2048
#define D_ 1024
#define B_ 8
#define KEXP 3072            // 3 * D : [h,l,h] x [h,h,l] fp16 expansion
#define NEGC 1e9f

typedef _Float16 f16;
typedef _Float16 f16x8 __attribute__((ext_vector_type(8)));
typedef float f32x4 __attribute__((ext_vector_type(4)));

// LDS swizzle for 128B rows: XOR chunk bits 4-6 with row bits 0-2 (involution,
// 16B-preserving). Balances a wave's 64-lane b128 fragment read to exactly
// 8 accesses/bank (minimum) and keeps staging rows contiguous.
__device__ __forceinline__ int swz128(int x) { return x ^ (((x >> 7) & 7) << 4); }

#define DSR(dst, addr, off) \
  asm volatile("ds_read_b128 %0, %1 offset:%c2" : "=v"(dst) : "v"(addr), "i"(off))
#define LGKM0 do { asm volatile("s_waitcnt lgkmcnt(0)" ::: "memory"); \
                   __builtin_amdgcn_sched_barrier(0); } while (0)
#define VMC(n) asm volatile("s_waitcnt vmcnt(%c0)" :: "i"(n) : "memory")
#define BAR() __builtin_amdgcn_s_barrier()

// ---------------------------------------------------------------------------
// K0: split fp32 -> fp16 hi/lo 3-term expansion, input pre-scaled by 64.
// pattern A (q): [h,l,h]   pattern B (k): [h,h,l];  blockIdx.y: 0=q, 1=k.
// ---------------------------------------------------------------------------
__global__ __launch_bounds__(256) void split_expand2(const float* __restrict__ qin,
                                                     const float* __restrict__ kin,
                                                     f16* __restrict__ qx,
                                                     f16* __restrict__ kx) {
  const int isB = blockIdx.y;
  const float* in = isB ? kin : qin;
  f16* out = isB ? kx : qx;
  size_t idx = (size_t)blockIdx.x * 256 + threadIdx.x;
  const float4* ip = (const float4*)(in + idx * 8);
  float4 a = ip[0], b = ip[1];
  float vv[8] = {a.x, a.y, a.z, a.w, b.x, b.y, b.z, b.w};
  union { f16 h[24]; uint4 u[3]; } o;
#pragma unroll
  for (int t = 0; t < 8; ++t) {
    float v = vv[t] * 64.0f;
    f16 h = (f16)v;
    float r = v - (float)h;      // exact (Sterbenz)
    f16 l = (f16)r;
    o.h[3 * t + 0] = h;
    o.h[3 * t + 1] = isB ? h : l;
    o.h[3 * t + 2] = isB ? l : h;
  }
  uint4* op = (uint4*)(out + idx * 24);
  op[0] = o.u[0]; op[1] = o.u[1]; op[2] = o.u[2];
}

// ---------------------------------------------------------------------------
// K0c: khT[b][d][j] = fp16(k[b][j][d])
// ---------------------------------------------------------------------------
__global__ __launch_bounds__(256) void transpose_cast(const float* __restrict__ k,
                                                      f16* __restrict__ khT) {
  __shared__ f16 tile[64][65];
  int j0 = blockIdx.x * 64, d0 = blockIdx.y * 64;
  size_t bz = blockIdx.z;
  const float* kb = k + bz * (size_t)S_ * D_;
  f16* ob = khT + bz * (size_t)D_ * S_;
#pragma unroll
  for (int i = 0; i < 16; ++i) {
    int e = threadIdx.x + i * 256;
    int r = e >> 6, c = e & 63;
    tile[c][r] = (f16)kb[(size_t)(j0 + r) * D_ + d0 + c];
  }
  __syncthreads();
#pragma unroll
  for (int i = 0; i < 16; ++i) {
    int e = threadIdx.x + i * 256;
    int r = e >> 6, c = e & 63;
    ob[(size_t)(d0 + r) * S_ + j0 + c] = tile[r][c];
  }
}

// ---------------------------------------------------------------------------
// 8-phase GEMM (B-transposed): C[m,n] = (sum_k A[m,k]*B[n,k]) * mult
// 256xBN tile, BK=64, 8 waves (2M x 4N), dbuf-2 LDS, m201-style schedule:
// per phase {asm ds_reads || 1-unit stage -> BAR -> lgkm0+schedbar -> prio1 ->
// MFMA -> prio0 -> [counted vmcnt @ph4/ph8] -> BAR}. Inline-asm ds_reads keep
// hipcc from inserting vmcnt(0) drains (LDS alias conservatism).
// Stage/publication/overwrite ledger (verified):
//  ph1:A1(v) ph2:B1(v) ph3:A0(u') ph4:B0(u')+vm ph5:A1(u') ph6:B1(u')
//  ph7:A0(v') ph8:B0(v')+vm ; vmcnt(2+RB) leaves last 2 units in flight.
// K-accumulation order per acc element is monotone in k -> bit-identical
// results vs previous rounds.
// ---------------------------------------------------------------------------
template <int KA, int NN, int BN>
__global__ __launch_bounds__(512, 2) void gemm8p(const f16* __restrict__ A,
                                                 const f16* __restrict__ Bm,
                                                 float* __restrict__ C,
                                                 const float* scale_ptr, float factor) {
  constexpr int NFQ = BN / 128;     // B frags / wave / phase (2 or 1)
  constexpr int RB = BN / 128;      // gloads / thread / B unit (2 or 1)
  constexpr int VMN = 2 + RB;       // counted vmcnt (leave last 2 units in flight)
  constexpr int NI = KA / 128;      // iterations (2 K-tiles each)
  __shared__ f16 AS[2][256 * 64];   // 2 x 32KB
  __shared__ f16 BS[2][BN * 64];    // 2 x (32|16)KB

  const int tid = threadIdx.x;
  const int lane = tid & 63, wave = tid >> 6;
  const int wm = wave >> 2, wn = wave & 3;        // 2 x 4 wave grid
  const int fr = lane & 15, kq = lane >> 4;

  // XCD-chunk swizzle (bijective: 64*cb % 8 == 0): each XCD gets a contiguous
  // chunk of (z,y,x) tile space -> B-panel reuse in its private L2.
  int lin = blockIdx.x + gridDim.x * blockIdx.y;
  int ntot = gridDim.x * gridDim.y;
  int nid = (lin & 7) * (ntot >> 3) + (lin >> 3);
  int bz = nid >> 6, rem = nid & 63;
  int bx = rem & 7, by = rem >> 3;

  const f16* Ab = A + (size_t)bz * S_ * KA + (size_t)bx * 256 * KA;
  const f16* Bb = Bm + (size_t)bz * NN * KA + (size_t)by * BN * KA;

  // fragment read base addresses (thread-const); per-read delta is imm offset
  const int T0 = fr * 128 + (((0 + kq) ^ (fr & 7)) << 4);
  const int T1 = fr * 128 + (((4 + kq) ^ (fr & 7)) << 4);
  uint32_t asbase = (uint32_t)(uintptr_t)(__attribute__((address_space(3))) f16*)&AS[0][0];
  uint32_t bsbase = (uint32_t)(uintptr_t)(__attribute__((address_space(3))) f16*)&BS[0][0];
  uint32_t aA[2][2], aB[2][2];
#pragma unroll
  for (int b = 0; b < 2; ++b) {
    aA[b][0] = asbase + b * 32768 + wm * 8192 + T0;
    aA[b][1] = asbase + b * 32768 + wm * 8192 + T1;
    aB[b][0] = bsbase + b * (BN * 128) + wn * (BN * 16) + T0;
    aB[b][1] = bsbase + b * (BN * 128) + wn * (BN * 16) + T1;
  }

  // staging: linear LDS dest (wave-uniform base), inverse-swizzled global src
  const int srl = tid >> 3;                                        // row in 8KB round
  const int sgc = ((((tid * 16) & 127) ^ (((tid >> 3) & 7) << 4)) >> 1);  // f16 col

  auto stgA = [&](int buf, int unit, int kt) {
#pragma unroll
    for (int i = 0; i < 2; ++i) {
      const f16* src = Ab + (size_t)(unit * 128 + i * 64 + srl) * KA + kt * 64 + sgc;
      __builtin_amdgcn_global_load_lds(
          (const __attribute__((address_space(1))) void*)src,
          (__attribute__((address_space(3))) void*)&AS[buf][unit * 8192 + i * 4096 + wave * 512],
          16, 0, 0);
    }
  };
  auto stgB = [&](int buf, int unit, int kt) {
#pragma unroll
    for (int i = 0; i < RB; ++i) {
      const f16* src = Bb + (size_t)(unit * (BN / 2) + i * 64 + srl) * KA + kt * 64 + sgc;
      __builtin_amdgcn_global_load_lds(
          (const __attribute__((address_space(1))) void*)src,
          (__attribute__((address_space(3))) void*)&BS[buf][unit * (BN * 32) + i * 4096 + wave * 512],
          16, 0, 0);
    }
  };

  f32x4 acc[2][2][4][2];
#pragma unroll
  for (int mh = 0; mh < 2; ++mh)
#pragma unroll
    for (int nh = 0; nh < 2; ++nh)
#pragma unroll
      for (int m = 0; m < 4; ++m)
#pragma unroll
        for (int n = 0; n < NFQ; ++n)
#pragma unroll
          for (int r = 0; r < 4; ++r) acc[mh][nh][m][n][r] = 0.0f;

#define PH(UB, MH, NH, STG_STMT, VM_STMT) do {                                          \
    f16x8 af0[4], af1[4], bf0[2], bf1[2];                                               \
    DSR(af0[0], aA[UB][0], (MH)*16384 + 0);                                             \
    DSR(af0[1], aA[UB][0], (MH)*16384 + 2048);                                          \
    DSR(af0[2], aA[UB][0], (MH)*16384 + 4096);                                          \
    DSR(af0[3], aA[UB][0], (MH)*16384 + 6144);                                          \
    DSR(af1[0], aA[UB][1], (MH)*16384 + 0);                                             \
    DSR(af1[1], aA[UB][1], (MH)*16384 + 2048);                                          \
    DSR(af1[2], aA[UB][1], (MH)*16384 + 4096);                                          \
    DSR(af1[3], aA[UB][1], (MH)*16384 + 6144);                                          \
    DSR(bf0[0], aB[UB][0], (NH)*(BN * 64) + 0);                                         \
    DSR(bf1[0], aB[UB][1], (NH)*(BN * 64) + 0);                                         \
    if constexpr (NFQ == 2) {                                                           \
      DSR(bf0[1], aB[UB][0], (NH)*(BN * 64) + 2048);                                    \
      DSR(bf1[1], aB[UB][1], (NH)*(BN * 64) + 2048);                                    \
    }                                                                                   \
    STG_STMT;                                                                           \
    BAR();                                                                              \
    LGKM0;                                                                              \
    __builtin_amdgcn_s_setprio(1);                                                      \
    _Pragma("unroll")                                                                   \
    for (int m = 0; m < 4; ++m) {                                                       \
      acc[MH][NH][m][0] = __builtin_amdgcn_mfma_f32_16x16x32_f16(af0[m], bf0[0], acc[MH][NH][m][0], 0, 0, 0); \
      acc[MH][NH][m][0] = __builtin_amdgcn_mfma_f32_16x16x32_f16(af1[m], bf1[0], acc[MH][NH][m][0], 0, 0, 0); \
      if constexpr (NFQ == 2) {                                                         \
        acc[MH][NH][m][1] = __builtin_amdgcn_mfma_f32_16x16x32_f16(af0[m], bf0[1], acc[MH][NH][m][1], 0, 0, 0); \
        acc[MH][NH][m][1] = __builtin_amdgcn_mfma_f32_16x16x32_f16(af1[m], bf1[1], acc[MH][NH][m][1], 0, 0, 0); \
      }                                                                                 \
    }                                                                                   \
    __builtin_amdgcn_s_setprio(0);                                                      \
    VM_STMT;                                                                            \
    BAR();                                                                              \
  } while (0)

  // prologue: tile0 full; tile1 A0,B0 (A1,B1 staged in iter0 ph1,2)
  stgA(0, 0, 0); stgB(0, 0, 0); stgA(0, 1, 0); stgB(0, 1, 0);
  stgA(1, 0, 1); stgB(1, 0, 1);
  VMC(0); BAR();

#pragma unroll 1
  for (int I = 0; I < NI; ++I) {
    const int v = 2 * I + 1, u2 = 2 * I + 2, v2 = 2 * I + 3;
    const bool st = (I + 1 < NI);
    PH(0, 0, 0, { stgA(1, 1, v); }, {});
    PH(0, 0, 1, { stgB(1, 1, v); }, {});
    PH(0, 1, 0, { if (st) stgA(0, 0, u2); }, {});
    PH(0, 1, 1, { if (st) stgB(0, 0, u2); }, { if (st) { VMC(VMN); } else { VMC(0); } });
    PH(1, 0, 0, { if (st) stgA(0, 1, u2); }, {});
    PH(1, 0, 1, { if (st) stgB(0, 1, u2); }, {});
    PH(1, 1, 0, { if (st) stgA(1, 0, v2); }, {});
    PH(1, 1, 1, { if (st) stgB(1, 0, v2); }, { if (st) { VMC(VMN); } else { VMC(0); } });
  }
#undef PH

  float scl = factor;
  if (scale_ptr != nullptr) scl = factor * scale_ptr[0];
  float* Cb = C + (size_t)bz * S_ * NN;
  const int r0 = bx * 256 + wm * 64 + kq * 4;
  const int c0 = by * BN + wn * (BN / 8) + fr;
#pragma unroll
  for (int mh = 0; mh < 2; ++mh)
#pragma unroll
    for (int nh = 0; nh < 2; ++nh)
#pragma unroll
      for (int m = 0; m < 4; ++m)
#pragma unroll
        for (int n = 0; n < NFQ; ++n)
#pragma unroll
          for (int r = 0; r < 4; ++r)
            Cb[(size_t)(r0 + mh * 128 + m * 16 + r) * NN + c0 + nh * (BN / 2) + n * 16] =
                acc[mh][nh][m][n][r] * scl;
}

// ---------------------------------------------------------------------------
// reductions
// ---------------------------------------------------------------------------
__device__ __forceinline__ float block_reduce_max(float v, float* red, int tid) {
#pragma unroll
  for (int o = 32; o > 0; o >>= 1) v = fmaxf(v, __shfl_xor(v, o, 64));
  __syncthreads();
  if ((tid & 63) == 0) red[tid >> 6] = v;
  __syncthreads();
  return fmaxf(fmaxf(red[0], red[1]), fmaxf(red[2], red[3]));
}
__device__ __forceinline__ float block_reduce_sum(float v, float* red, int tid) {
#pragma unroll
  for (int o = 32; o > 0; o >>= 1) v += __shfl_xor(v, o, 64);
  __syncthreads();
  if ((tid & 63) == 0) red[4 + (tid >> 6)] = v;
  __syncthreads();
  return (red[4] + red[5]) + (red[6] + red[7]);
}

// ---------------------------------------------------------------------------
// K2: row softmax for VALID query rows; padding rows -> P row = 0.
// ---------------------------------------------------------------------------
__global__ __launch_bounds__(256) void softmax_rows(const float* __restrict__ scores,
                                                    const int* __restrict__ mask,
                                                    f16* __restrict__ P, int b0) {
  __shared__ float red[8];
  const int q = blockIdx.x, bl = blockIdx.y, bg = b0 + bl;
  const int tid = threadIdx.x;
  const float* srow = scores + ((size_t)bl * S_ + q) * S_;
  f16* prow = P + ((size_t)bl * S_ + q) * S_;
  if (mask[bg * S_ + q] == 0) {
    uint4 z = {0, 0, 0, 0};
    ((uint4*)prow)[tid] = z;
    return;
  }
  const int j0 = tid * 8;
  float4 s0v = *(const float4*)(srow + j0);
  float4 s1v = *(const float4*)(srow + j0 + 4);
  int4 m0 = *(const int4*)(mask + (size_t)bg * S_ + j0);
  int4 m1 = *(const int4*)(mask + (size_t)bg * S_ + j0 + 4);
  float sv[8] = {s0v.x, s0v.y, s0v.z, s0v.w, s1v.x, s1v.y, s1v.z, s1v.w};
  int mk[8] = {m0.x, m0.y, m0.z, m0.w, m1.x, m1.y, m1.z, m1.w};
  int fl[8];
  float lm = -3.4e38f;
#pragma unroll
  for (int i = 0; i < 8; ++i) {
    fl[i] = (j0 + i <= q) && (mk[i] != 0);
    if (fl[i]) lm = fmaxf(lm, sv[i]);
  }
  float m = block_reduce_max(lm, red, tid);
  float ls = 0.0f;
#pragma unroll
  for (int i = 0; i < 8; ++i) {
    float e = fl[i] ? expf(sv[i] - m) : 0.0f;
    sv[i] = e; ls += e;
  }
  float sum = block_reduce_sum(ls, red, tid);
  float inv = 1.0f / sum;
  union { f16 h[8]; uint4 u; } ow;
#pragma unroll
  for (int i = 0; i < 8; ++i) ow.h[i] = (f16)(sv[i] * inv);
  *(uint4*)(prow + j0) = ow.u;
}

// ---------------------------------------------------------------------------
// K4: padding query rows — replicate fp32 quantization of fl(s-1e9):
// uniform mean over the top 64-wide bucket; boundary entries get an exact
// (double) recompute. Ordered match list via block prefix scan.
// ---------------------------------------------------------------------------
__global__ __launch_bounds__(256) void padrows(const float* __restrict__ scores,
                                               const int* __restrict__ mask,
                                               const float* __restrict__ qg,
                                               const float* __restrict__ kg,
                                               const float* __restrict__ scale_ptr,
                                               float* __restrict__ out, int b0) {
  const int q = blockIdx.x, bl = blockIdx.y, bg = b0 + bl;
  if (mask[bg * S_ + q] != 0) return;
  const int tid = threadIdx.x;
  __shared__ int idxs[S_];
  __shared__ int scn[256];
  __shared__ float red[8];
  const float* srow = scores + ((size_t)bl * S_ + q) * S_;
  const float scl = scale_ptr[0];
  const int j0 = tid * 8;

  float4 s0v = *(const float4*)(srow + j0);
  float4 s1v = *(const float4*)(srow + j0 + 4);
  float sv[8] = {s0v.x, s0v.y, s0v.z, s0v.w, s1v.x, s1v.y, s1v.z, s1v.w};
  float vv[8];
  float lm = -3.4e38f;
#pragma unroll
  for (int i = 0; i < 8; ++i) {
    vv[i] = sv[i] - NEGC;
    lm = fmaxf(lm, vv[i]);
  }
  float g0 = block_reduce_max(lm, red, tid);

  float lm2 = -3.4e38f;
#pragma unroll 1
  for (int i = 0; i < 8; ++i) {
    float s = sv[i];
    float t = s * (1.0f / 64.0f);
    float rn = rintf(t);
    float dist = (0.5f - fabsf(t - rn)) * 64.0f;
    float v = vv[i];
    if (dist < 1e-3f && v >= g0 - 64.5f) {
      const float* qr = qg + ((size_t)bg * S_ + q) * D_;
      const float* kr = kg + ((size_t)bg * S_ + j0 + i) * D_;
      double acc = 0.0;
      for (int t2 = 0; t2 < D_; ++t2) acc += (double)qr[t2] * (double)kr[t2];
      float sx = (float)acc * scl;
      v = sx - NEGC;
    }
    vv[i] = v;
    lm2 = fmaxf(lm2, v);
  }
  float gf = block_reduce_max(lm2, red, tid);

  int local = 0, flags = 0;
#pragma unroll
  for (int i = 0; i < 8; ++i) {
    int mt = (vv[i] == gf) ? 1 : 0;
    flags |= mt << i;
    local += mt;
  }
  scn[tid] = local;
  __syncthreads();
#pragma unroll
  for (int o = 1; o < 256; o <<= 1) {
    int v2 = (tid >= o) ? scn[tid - o] : 0;
    __syncthreads();
    scn[tid] += v2;
    __syncthreads();
  }
  int total = scn[255];
  int base = scn[tid] - local;
  int w = 0;
#pragma unroll
  for (int i = 0; i < 8; ++i)
    if ((flags >> i) & 1) idxs[base + (w++)] = j0 + i;
  __syncthreads();

  const float* kb = kg + (size_t)bg * S_ * D_;
  float a0 = 0, a1 = 0, a2 = 0, a3 = 0;
#pragma unroll 4
  for (int m2 = 0; m2 < total; ++m2) {
    const float4 kv = *(const float4*)(kb + (size_t)idxs[m2] * D_ + tid * 4);
    a0 += kv.x; a1 += kv.y; a2 += kv.z; a3 += kv.w;
  }
  float invc = 1.0f / (float)total;
  float4 o = {a0 * invc, a1 * invc, a2 * invc, a3 * invc};
  *(float4*)(out + ((size_t)bg * S_ + q) * D_ + tid * 4) = o;
}

// ---------------------------------------------------------------------------
extern "C" void kernel_launch(void* const* d_in, const int* in_sizes, int n_in,
                              void* d_out, int out_size, void* d_ws, size_t ws_size,
                              hipStream_t stream) {
  (void)in_sizes; (void)n_in; (void)out_size;
  const float* q = (const float*)d_in[0];
  const float* k = (const float*)d_in[1];
  const int* mask = (const int*)d_in[2];
  const float* scale = (const float*)d_in[3];
  float* out = (float*)d_out;

  const size_t per_qx = (size_t)S_ * KEXP * 2;     // 12.58 MB
  const size_t per_khT = (size_t)D_ * S_ * 2;      //  4.19 MB
  const size_t per_sc = (size_t)S_ * S_ * 4;       // 16.78 MB
  const size_t per_batch = 2 * per_qx + per_khT + per_sc;  // P overlays qx

  int nb = (int)(ws_size / per_batch);
  if (nb > 4) nb = 4;   // 64*nb GEMM blocks: nb=4 -> 256 = exactly 1/CU
  if (nb < 1) nb = 1;

  char* w = (char*)d_ws;
  f16* qx = (f16*)w;
  f16* kx = (f16*)(w + (size_t)nb * per_qx);
  f16* khT = (f16*)(w + (size_t)nb * per_qx * 2);
  float* sc = (float*)(w + (size_t)nb * (per_qx * 2 + per_khT));
  f16* P = qx;                                     // overlay

  for (int b0 = 0; b0 < B_; b0 += nb) {
    int cb = (B_ - b0 < nb) ? (B_ - b0) : nb;
    const float* qb = q + (size_t)b0 * S_ * D_;
    const float* kb = k + (size_t)b0 * S_ * D_;

    int blocks0 = cb * ((S_ * D_ / 8) / 256);  // cb * 1024
    split_expand2<<<dim3(blocks0, 2), dim3(256), 0, stream>>>(qb, kb, qx, kx);
    transpose_cast<<<dim3(S_ / 64, D_ / 64, cb), dim3(256), 0, stream>>>(kb, khT);

    // scores = (q.k) * scale : factor 2^-12 undoes the 64x prescale on q,k
    gemm8p<KEXP, S_, 256><<<dim3(64, cb), dim3(512), 0, stream>>>(
        qx, kx, sc, scale, 0.000244140625f);

    softmax_rows<<<dim3(S_, cb), dim3(256), 0, stream>>>(sc, mask, P, b0);

    gemm8p<S_, D_, 128><<<dim3(64, cb), dim3(512), 0, stream>>>(
        P, khT, out + (size_t)b0 * S_ * D_, nullptr, 1.0f);

    padrows<<<dim3(S_, cb), dim3(256), 0, stream>>>(sc, mask, q, k, scale, out, b0);
  }
}

// Round 6
// 545.676 us; speedup vs baseline: 1.4208x; 1.0609x over previous
//
#include <hip/hip_runtime.h>
#include <hip/hip_bf16.h>
#include <stdint.h>

#define S_ 2048
#define D_ 1024
#define B_ 8
#define KEXP 3072            // 3 * D : [h,l,h] x [h,h,l] fp16 expansion
#define NEGC 1e9f

typedef _Float16 f16;
typedef _Float16 f16x8 __attribute__((ext_vector_type(8)));
typedef float f32x4 __attribute__((ext_vector_type(4)));

#define DSR(dst, addr, off) \
  asm volatile("ds_read_b128 %0, %1 offset:%c2" : "=v"(dst) : "v"(addr), "i"(off))
#define LGKM0 do { asm volatile("s_waitcnt lgkmcnt(0)" ::: "memory"); \
                   __builtin_amdgcn_sched_barrier(0); } while (0)
#define VMC(n) asm volatile("s_waitcnt vmcnt(%c0)" :: "i"(n) : "memory")
#define BAR() __builtin_amdgcn_s_barrier()

// ---------------------------------------------------------------------------
// K0: split fp32 -> fp16 hi/lo 3-term expansion, input pre-scaled by 64.
// pattern A (q): [h,l,h]   pattern B (k): [h,h,l];  blockIdx.y: 0=q, 1=k.
// ---------------------------------------------------------------------------
__global__ __launch_bounds__(256) void split_expand2(const float* __restrict__ qin,
                                                     const float* __restrict__ kin,
                                                     f16* __restrict__ qx,
                                                     f16* __restrict__ kx) {
  const int isB = blockIdx.y;
  const float* in = isB ? kin : qin;
  f16* out = isB ? kx : qx;
  size_t idx = (size_t)blockIdx.x * 256 + threadIdx.x;
  const float4* ip = (const float4*)(in + idx * 8);
  float4 a = ip[0], b = ip[1];
  float vv[8] = {a.x, a.y, a.z, a.w, b.x, b.y, b.z, b.w};
  union { f16 h[24]; uint4 u[3]; } o;
#pragma unroll
  for (int t = 0; t < 8; ++t) {
    float v = vv[t] * 64.0f;
    f16 h = (f16)v;
    float r = v - (float)h;      // exact (Sterbenz)
    f16 l = (f16)r;
    o.h[3 * t + 0] = h;
    o.h[3 * t + 1] = isB ? h : l;
    o.h[3 * t + 2] = isB ? l : h;
  }
  uint4* op = (uint4*)(out + idx * 24);
  op[0] = o.u[0]; op[1] = o.u[1]; op[2] = o.u[2];
}

// ---------------------------------------------------------------------------
// K0c: khT[b][d][j] = fp16(k[b][j][d])
// ---------------------------------------------------------------------------
__global__ __launch_bounds__(256) void transpose_cast(const float* __restrict__ k,
                                                      f16* __restrict__ khT) {
  __shared__ f16 tile[64][65];
  int j0 = blockIdx.x * 64, d0 = blockIdx.y * 64;
  size_t bz = blockIdx.z;
  const float* kb = k + bz * (size_t)S_ * D_;
  f16* ob = khT + bz * (size_t)D_ * S_;
#pragma unroll
  for (int i = 0; i < 16; ++i) {
    int e = threadIdx.x + i * 256;
    int r = e >> 6, c = e & 63;
    tile[c][r] = (f16)kb[(size_t)(j0 + r) * D_ + d0 + c];
  }
  __syncthreads();
#pragma unroll
  for (int i = 0; i < 16; ++i) {
    int e = threadIdx.x + i * 256;
    int r = e >> 6, c = e & 63;
    ob[(size_t)(d0 + r) * S_ + j0 + c] = tile[r][c];
  }
}

// ---------------------------------------------------------------------------
// 8-phase GEMM (B-transposed), snake-order fragment reuse.
// 256xBN tile, BK=64, 8 waves (2M x 4N), dbuf-2 LDS.
// Phase order per K-tile: (MH0,NH0)->(MH0,NH1)->(MH1,NH1)->(MH1,NH0):
// A-frags read once per MH (reused across 2 NH phases); B-frags reused
// across the MH pair; NH0 re-read at P4. Reads/phase: 12,4,8,4 (was 12x4).
// Stage ledger (every overwrite-vs-read + publication pair verified):
//  ph1: A1(v)          [buf1-A1: prev read ph7']       reads: A-u0,B-u0 buf0
//  ph2: B0(v)+B1(v)    [buf1-B: prev reads ph5/6/8']   reads: B-u1 buf0
//  ph3: A0(u2)         [buf0-A0: read ph1]             reads: A-u1 buf0
//  ph4: A1(u2) VMC(4)  [buf0-A1: read ph3]             reads: B-u0 buf0 (re)
//  ph5: B1(u2)         [buf0-B1: read ph2]             reads: A-u0,B-u0 buf1
//  ph6: B0(u2)         [buf0-B0: reads ph1,ph4]        reads: B-u1 buf1
//  ph7: A0(v2)         [buf1-A0: read ph5]             reads: A-u1 buf1
//  ph8: --     VMC(2)                                  reads: B-u0 buf1 (re)
// VMC(4)@ph4 leaves ph3+ph4 (4 gloads) in flight, publishes ph1-2 for ph5;
// VMC(2)@ph8 leaves ph7 (2 gloads), publishes ph3-6 for next ph1.
// Per-element k-accumulation order unchanged -> bit-identical results.
// ---------------------------------------------------------------------------
template <int KA, int NN, int BN>
__global__ __launch_bounds__(512, 2) void gemm8p(const f16* __restrict__ A,
                                                 const f16* __restrict__ Bm,
                                                 float* __restrict__ C,
                                                 const float* scale_ptr, float factor) {
  constexpr int NFQ = BN / 128;     // B frags per phase (2 or 1)
  constexpr int RB = BN / 256 + (BN == 128 ? 0 : 0);  // (kept for clarity)
  constexpr int NI = KA / 128;      // iterations (2 K-tiles each)
  __shared__ f16 AS[2][256 * 64];   // 2 x 32KB
  __shared__ f16 BS[2][BN * 64];    // 2 x (32|16)KB

  const int tid = threadIdx.x;
  const int lane = tid & 63, wave = tid >> 6;
  const int wm = wave >> 2, wn = wave & 3;        // 2 x 4 wave grid
  const int fr = lane & 15, kq = lane >> 4;

  // XCD-chunk swizzle (bijective: 64*cb % 8 == 0)
  int lin = blockIdx.x + gridDim.x * blockIdx.y;
  int ntot = gridDim.x * gridDim.y;
  int nid = (lin & 7) * (ntot >> 3) + (lin >> 3);
  int bz = nid >> 6, rem = nid & 63;
  int bx = rem & 7, by = rem >> 3;

  const f16* Ab = A + (size_t)bz * S_ * KA + (size_t)bx * 256 * KA;
  const f16* Bb = Bm + (size_t)bz * NN * KA + (size_t)by * BN * KA;

  // fragment read base addresses (thread-const); per-read delta is imm offset
  const int T0 = fr * 128 + (((0 + kq) ^ (fr & 7)) << 4);
  const int T1 = fr * 128 + (((4 + kq) ^ (fr & 7)) << 4);
  uint32_t asbase = (uint32_t)(uintptr_t)(__attribute__((address_space(3))) f16*)&AS[0][0];
  uint32_t bsbase = (uint32_t)(uintptr_t)(__attribute__((address_space(3))) f16*)&BS[0][0];
  uint32_t aA[2][2], aB[2][2];
#pragma unroll
  for (int b = 0; b < 2; ++b) {
    aA[b][0] = asbase + b * 32768 + wm * 8192 + T0;
    aA[b][1] = asbase + b * 32768 + wm * 8192 + T1;
    aB[b][0] = bsbase + b * (BN * 128) + wn * (BN * 16) + T0;
    aB[b][1] = bsbase + b * (BN * 128) + wn * (BN * 16) + T1;
  }

  // staging: linear LDS dest (wave-uniform base), inverse-swizzled global src
  const int srl = tid >> 3;                                        // row in 8KB round
  const int sgc = ((((tid * 16) & 127) ^ (((tid >> 3) & 7) << 4)) >> 1);  // f16 col

  auto stgA = [&](int buf, int unit, int kt) {
#pragma unroll
    for (int i = 0; i < 2; ++i) {
      const f16* src = Ab + (size_t)(unit * 128 + i * 64 + srl) * KA + kt * 64 + sgc;
      __builtin_amdgcn_global_load_lds(
          (const __attribute__((address_space(1))) void*)src,
          (__attribute__((address_space(3))) void*)&AS[buf][unit * 8192 + i * 4096 + wave * 512],
          16, 0, 0);
    }
  };
  auto stgB = [&](int buf, int unit, int kt) {
#pragma unroll
    for (int i = 0; i < BN / 128; ++i) {
      const f16* src = Bb + (size_t)(unit * (BN / 2) + i * 64 + srl) * KA + kt * 64 + sgc;
      __builtin_amdgcn_global_load_lds(
          (const __attribute__((address_space(1))) void*)src,
          (__attribute__((address_space(3))) void*)&BS[buf][unit * (BN * 32) + i * 4096 + wave * 512],
          16, 0, 0);
    }
  };

  f32x4 acc[2][2][4][2];
#pragma unroll
  for (int mh = 0; mh < 2; ++mh)
#pragma unroll
    for (int nh = 0; nh < 2; ++nh)
#pragma unroll
      for (int m = 0; m < 4; ++m)
#pragma unroll
        for (int n = 0; n < NFQ; ++n)
#pragma unroll
          for (int r = 0; r < 4; ++r) acc[mh][nh][m][n][r] = 0.0f;

#define RD_A(UB, MH) do {                        \
    DSR(af[0], aA[UB][0], (MH)*16384 + 0);       \
    DSR(af[1], aA[UB][0], (MH)*16384 + 2048);    \
    DSR(af[2], aA[UB][0], (MH)*16384 + 4096);    \
    DSR(af[3], aA[UB][0], (MH)*16384 + 6144);    \
    DSR(af[4], aA[UB][1], (MH)*16384 + 0);       \
    DSR(af[5], aA[UB][1], (MH)*16384 + 2048);    \
    DSR(af[6], aA[UB][1], (MH)*16384 + 4096);    \
    DSR(af[7], aA[UB][1], (MH)*16384 + 6144);    \
  } while (0)

#define RD_B(UB, NH) do {                             \
    DSR(bf[0], aB[UB][0], (NH) * (BN * 64) + 0);      \
    DSR(bf[1], aB[UB][1], (NH) * (BN * 64) + 0);      \
    if constexpr (NFQ == 2) {                         \
      DSR(bf[2], aB[UB][0], (NH) * (BN * 64) + 2048); \
      DSR(bf[3], aB[UB][1], (NH) * (BN * 64) + 2048); \
    }                                                 \
  } while (0)

#define MM(MH, NH) do {                                                                   \
    __builtin_amdgcn_s_setprio(1);                                                        \
    _Pragma("unroll")                                                                     \
    for (int m = 0; m < 4; ++m) {                                                         \
      acc[MH][NH][m][0] = __builtin_amdgcn_mfma_f32_16x16x32_f16(af[m], bf[0], acc[MH][NH][m][0], 0, 0, 0);     \
      acc[MH][NH][m][0] = __builtin_amdgcn_mfma_f32_16x16x32_f16(af[4 + m], bf[1], acc[MH][NH][m][0], 0, 0, 0); \
      if constexpr (NFQ == 2) {                                                           \
        acc[MH][NH][m][1] = __builtin_amdgcn_mfma_f32_16x16x32_f16(af[m], bf[2], acc[MH][NH][m][1], 0, 0, 0);     \
        acc[MH][NH][m][1] = __builtin_amdgcn_mfma_f32_16x16x32_f16(af[4 + m], bf[3], acc[MH][NH][m][1], 0, 0, 0); \
      }                                                                                   \
    }                                                                                     \
    __builtin_amdgcn_s_setprio(0);                                                        \
  } while (0)

  // prologue: tile0 complete into buf0; tile1 A-unit0 into buf1
  stgA(0, 0, 0); stgA(0, 1, 0); stgB(0, 0, 0); stgB(0, 1, 0);
  stgA(1, 0, 1);
  VMC(0); BAR();

#pragma unroll 1
  for (int I = 0; I < NI; ++I) {
    const int v = 2 * I + 1, u2 = 2 * I + 2, v2 = 2 * I + 3;
    const bool st = (I + 1 < NI);
    f16x8 af[8], bf[4];
    // ---- UB0 (tile u = 2I)
    RD_A(0, 0); RD_B(0, 0); stgA(1, 1, v);
    BAR(); LGKM0; MM(0, 0); BAR();
    RD_B(0, 1); stgB(1, 0, v); stgB(1, 1, v);
    BAR(); LGKM0; MM(0, 1); BAR();
    RD_A(0, 1); if (st) stgA(0, 0, u2);
    BAR(); LGKM0; MM(1, 1); BAR();
    RD_B(0, 0); if (st) stgA(0, 1, u2);
    BAR(); LGKM0; MM(1, 0);
    if (st) { VMC(4); } else { VMC(0); }
    BAR();
    // ---- UB1 (tile v = 2I+1)
    RD_A(1, 0); RD_B(1, 0); if (st) stgB(0, 1, u2);
    BAR(); LGKM0; MM(0, 0); BAR();
    RD_B(1, 1); if (st) stgB(0, 0, u2);
    BAR(); LGKM0; MM(0, 1); BAR();
    RD_A(1, 1); if (st) stgA(1, 0, v2);
    BAR(); LGKM0; MM(1, 1); BAR();
    RD_B(1, 0);
    BAR(); LGKM0; MM(1, 0);
    if (st) { VMC(2); }
    BAR();
  }
#undef RD_A
#undef RD_B
#undef MM

  float scl = factor;
  if (scale_ptr != nullptr) scl = factor * scale_ptr[0];
  float* Cb = C + (size_t)bz * S_ * NN;
  const int r0 = bx * 256 + wm * 64 + kq * 4;
  const int c0 = by * BN + wn * (BN / 8) + fr;
#pragma unroll
  for (int mh = 0; mh < 2; ++mh)
#pragma unroll
    for (int nh = 0; nh < 2; ++nh)
#pragma unroll
      for (int m = 0; m < 4; ++m)
#pragma unroll
        for (int n = 0; n < NFQ; ++n)
#pragma unroll
          for (int r = 0; r < 4; ++r)
            Cb[(size_t)(r0 + mh * 128 + m * 16 + r) * NN + c0 + nh * (BN / 2) + n * 16] =
                acc[mh][nh][m][n][r] * scl;
}

// ---------------------------------------------------------------------------
// reductions
// ---------------------------------------------------------------------------
__device__ __forceinline__ float block_reduce_max(float v, float* red, int tid) {
#pragma unroll
  for (int o = 32; o > 0; o >>= 1) v = fmaxf(v, __shfl_xor(v, o, 64));
  __syncthreads();
  if ((tid & 63) == 0) red[tid >> 6] = v;
  __syncthreads();
  return fmaxf(fmaxf(red[0], red[1]), fmaxf(red[2], red[3]));
}
__device__ __forceinline__ float block_reduce_sum(float v, float* red, int tid) {
#pragma unroll
  for (int o = 32; o > 0; o >>= 1) v += __shfl_xor(v, o, 64);
  __syncthreads();
  if ((tid & 63) == 0) red[4 + (tid >> 6)] = v;
  __syncthreads();
  return (red[4] + red[5]) + (red[6] + red[7]);
}

// ---------------------------------------------------------------------------
// K2: row softmax for VALID query rows; padding rows -> P row = 0.
// ---------------------------------------------------------------------------
__global__ __launch_bounds__(256) void softmax_rows(const float* __restrict__ scores,
                                                    const int* __restrict__ mask,
                                                    f16* __restrict__ P, int b0) {
  __shared__ float red[8];
  const int q = blockIdx.x, bl = blockIdx.y, bg = b0 + bl;
  const int tid = threadIdx.x;
  const float* srow = scores + ((size_t)bl * S_ + q) * S_;
  f16* prow = P + ((size_t)bl * S_ + q) * S_;
  if (mask[bg * S_ + q] == 0) {
    uint4 z = {0, 0, 0, 0};
    ((uint4*)prow)[tid] = z;
    return;
  }
  const int j0 = tid * 8;
  float4 s0v = *(const float4*)(srow + j0);
  float4 s1v = *(const float4*)(srow + j0 + 4);
  int4 m0 = *(const int4*)(mask + (size_t)bg * S_ + j0);
  int4 m1 = *(const int4*)(mask + (size_t)bg * S_ + j0 + 4);
  float sv[8] = {s0v.x, s0v.y, s0v.z, s0v.w, s1v.x, s1v.y, s1v.z, s1v.w};
  int mk[8] = {m0.x, m0.y, m0.z, m0.w, m1.x, m1.y, m1.z, m1.w};
  int fl[8];
  float lm = -3.4e38f;
#pragma unroll
  for (int i = 0; i < 8; ++i) {
    fl[i] = (j0 + i <= q) && (mk[i] != 0);
    if (fl[i]) lm = fmaxf(lm, sv[i]);
  }
  float m = block_reduce_max(lm, red, tid);
  float ls = 0.0f;
#pragma unroll
  for (int i = 0; i < 8; ++i) {
    float e = fl[i] ? expf(sv[i] - m) : 0.0f;
    sv[i] = e; ls += e;
  }
  float sum = block_reduce_sum(ls, red, tid);
  float inv = 1.0f / sum;
  union { f16 h[8]; uint4 u; } ow;
#pragma unroll
  for (int i = 0; i < 8; ++i) ow.h[i] = (f16)(sv[i] * inv);
  *(uint4*)(prow + j0) = ow.u;
}

// ---------------------------------------------------------------------------
// K4: padding query rows — replicate fp32 quantization of fl(s-1e9):
// uniform mean over the top 64-wide bucket; boundary entries get an exact
// (double) recompute. Ordered match list via block prefix scan.
// ---------------------------------------------------------------------------
__global__ __launch_bounds__(256) void padrows(const float* __restrict__ scores,
                                               const int* __restrict__ mask,
                                               const float* __restrict__ qg,
                                               const float* __restrict__ kg,
                                               const float* __restrict__ scale_ptr,
                                               float* __restrict__ out, int b0) {
  const int q = blockIdx.x, bl = blockIdx.y, bg = b0 + bl;
  if (mask[bg * S_ + q] != 0) return;
  const int tid = threadIdx.x;
  __shared__ int idxs[S_];
  __shared__ int scn[256];
  __shared__ float red[8];
  const float* srow = scores + ((size_t)bl * S_ + q) * S_;
  const float scl = scale_ptr[0];
  const int j0 = tid * 8;

  float4 s0v = *(const float4*)(srow + j0);
  float4 s1v = *(const float4*)(srow + j0 + 4);
  float sv[8] = {s0v.x, s0v.y, s0v.z, s0v.w, s1v.x, s1v.y, s1v.z, s1v.w};
  float vv[8];
  float lm = -3.4e38f;
#pragma unroll
  for (int i = 0; i < 8; ++i) {
    vv[i] = sv[i] - NEGC;
    lm = fmaxf(lm, vv[i]);
  }
  float g0 = block_reduce_max(lm, red, tid);

  float lm2 = -3.4e38f;
#pragma unroll 1
  for (int i = 0; i < 8; ++i) {
    float s = sv[i];
    float t = s * (1.0f / 64.0f);
    float rn = rintf(t);
    float dist = (0.5f - fabsf(t - rn)) * 64.0f;
    float v = vv[i];
    if (dist < 1e-3f && v >= g0 - 64.5f) {
      const float* qr = qg + ((size_t)bg * S_ + q) * D_;
      const float* kr = kg + ((size_t)bg * S_ + j0 + i) * D_;
      double acc = 0.0;
      for (int t2 = 0; t2 < D_; ++t2) acc += (double)qr[t2] * (double)kr[t2];
      float sx = (float)acc * scl;
      v = sx - NEGC;
    }
    vv[i] = v;
    lm2 = fmaxf(lm2, v);
  }
  float gf = block_reduce_max(lm2, red, tid);

  int local = 0, flags = 0;
#pragma unroll
  for (int i = 0; i < 8; ++i) {
    int mt = (vv[i] == gf) ? 1 : 0;
    flags |= mt << i;
    local += mt;
  }
  scn[tid] = local;
  __syncthreads();
#pragma unroll
  for (int o = 1; o < 256; o <<= 1) {
    int v2 = (tid >= o) ? scn[tid - o] : 0;
    __syncthreads();
    scn[tid] += v2;
    __syncthreads();
  }
  int total = scn[255];
  int base = scn[tid] - local;
  int w = 0;
#pragma unroll
  for (int i = 0; i < 8; ++i)
    if ((flags >> i) & 1) idxs[base + (w++)] = j0 + i;
  __syncthreads();

  const float* kb = kg + (size_t)bg * S_ * D_;
  float a0 = 0, a1 = 0, a2 = 0, a3 = 0;
#pragma unroll 4
  for (int m2 = 0; m2 < total; ++m2) {
    const float4 kv = *(const float4*)(kb + (size_t)idxs[m2] * D_ + tid * 4);
    a0 += kv.x; a1 += kv.y; a2 += kv.z; a3 += kv.w;
  }
  float invc = 1.0f / (float)total;
  float4 o = {a0 * invc, a1 * invc, a2 * invc, a3 * invc};
  *(float4*)(out + ((size_t)bg * S_ + q) * D_ + tid * 4) = o;
}

// ---------------------------------------------------------------------------
extern "C" void kernel_launch(void* const* d_in, const int* in_sizes, int n_in,
                              void* d_out, int out_size, void* d_ws, size_t ws_size,
                              hipStream_t stream) {
  (void)in_sizes; (void)n_in; (void)out_size;
  const float* q = (const float*)d_in[0];
  const float* k = (const float*)d_in[1];
  const int* mask = (const int*)d_in[2];
  const float* scale = (const float*)d_in[3];
  float* out = (float*)d_out;

  const size_t per_qx = (size_t)S_ * KEXP * 2;     // 12.58 MB
  const size_t per_khT = (size_t)D_ * S_ * 2;      //  4.19 MB
  const size_t per_sc = (size_t)S_ * S_ * 4;       // 16.78 MB
  const size_t per_batch = 2 * per_qx + per_khT + per_sc;  // P overlays qx

  int nb = (int)(ws_size / per_batch);
  if (nb > 4) nb = 4;   // 64*nb GEMM blocks: nb=4 -> 256 = exactly 1/CU
  if (nb < 1) nb = 1;

  char* w = (char*)d_ws;
  f16* qx = (f16*)w;
  f16* kx = (f16*)(w + (size_t)nb * per_qx);
  f16* khT = (f16*)(w + (size_t)nb * per_qx * 2);
  float* sc = (float*)(w + (size_t)nb * (per_qx * 2 + per_khT));
  f16* P = qx;                                     // overlay

  for (int b0 = 0; b0 < B_; b0 += nb) {
    int cb = (B_ - b0 < nb) ? (B_ - b0) : nb;
    const float* qb = q + (size_t)b0 * S_ * D_;
    const float* kb = k + (size_t)b0 * S_ * D_;

    int blocks0 = cb * ((S_ * D_ / 8) / 256);  // cb * 1024
    split_expand2<<<dim3(blocks0, 2), dim3(256), 0, stream>>>(qb, kb, qx, kx);
    transpose_cast<<<dim3(S_ / 64, D_ / 64, cb), dim3(256), 0, stream>>>(kb, khT);

    // scores = (q.k) * scale : factor 2^-12 undoes the 64x prescale on q,k
    gemm8p<KEXP, S_, 256><<<dim3(64, cb), dim3(512), 0, stream>>>(
        qx, kx, sc, scale, 0.000244140625f);

    softmax_rows<<<dim3(S_, cb), dim3(256), 0, stream>>>(sc, mask, P, b0);

    gemm8p<S_, D_, 128><<<dim3(64, cb), dim3(512), 0, stream>>>(
        P, khT, out + (size_t)b0 * S_ * D_, nullptr, 1.0f);

    padrows<<<dim3(S_, cb), dim3(256), 0, stream>>>(sc, mask, q, k, scale, out, b0);
  }
}